// Round 9
// baseline (283.786 us; speedup 1.0000x reference)
//
#include <hip/hip_runtime.h>
#include <math.h>

// B=4, S=2048, D=1024, H=16, HD=64
#define SEQ 2048
#define DIM 1024
#define NH 16
#define HD 64
#define QKV_LD 3072

typedef __attribute__((ext_vector_type(8))) __bf16 bf16x8;
typedef __attribute__((ext_vector_type(8))) unsigned short u16x8;
typedef __attribute__((ext_vector_type(4))) unsigned short u16x4;
typedef __attribute__((ext_vector_type(4))) float f32x4;

// may_alias u32 for type-punned LDS writes (round-2 NaN post-mortem: TBAA
// hoisted ds_reads above ds_writes). Do NOT revert to plain int*.
typedef unsigned int __attribute__((may_alias)) u32a;

// float -> bf16 bits, round-to-nearest-even (v4-proven)
__device__ __forceinline__ unsigned short f2b(float f) {
  unsigned int b = __builtin_bit_cast(unsigned int, f);
  return (unsigned short)((b + 0x7fffu + ((b >> 16) & 1u)) >> 16);
}

__device__ __forceinline__ void gload_lds16(const void* g, void* l) {
  __builtin_amdgcn_global_load_lds((const __attribute__((address_space(1))) void*)g,
                                   (__attribute__((address_space(3))) void*)l,
                                   16, 0, 0);
}

// alias-safe aligned 16B LDS fragment load (memcpy: no TBAA reordering vs
// the u16/u64 stores into the same LDS)
__device__ __forceinline__ bf16x8 ld_frag16(const unsigned short* p) {
  bf16x8 r;
  __builtin_memcpy(&r, __builtin_assume_aligned((void*)p, 16), 16);
  return r;
}

// ---------------- pre-pass kernels ----------------

__global__ void to_bf16_kernel(const float* __restrict__ x,
                               unsigned short* __restrict__ y, int n) {
  int i = (blockIdx.x * blockDim.x + threadIdx.x) * 4;
  if (i >= n) return;
  float4 v = *(const float4*)(x + i);
  u16x4 o;
  o.x = f2b(v.x); o.y = f2b(v.y); o.z = f2b(v.z); o.w = f2b(v.w);
  *(u16x4*)(y + i) = o;
}

// W [K][N] fp32 -> WT [N][K] bf16
__global__ void transpose_to_bf16_kernel(const float* __restrict__ W,
                                         unsigned short* __restrict__ WT,
                                         int K, int N) {
  __shared__ float tile[32][33];
  const int n0 = blockIdx.x * 32, k0 = blockIdx.y * 32;
  const int tx = threadIdx.x, ty = threadIdx.y;
  tile[ty][tx] = W[(size_t)(k0 + ty) * N + n0 + tx];
  __syncthreads();
  WT[(size_t)(n0 + ty) * K + k0 + tx] = f2b(tile[tx][ty]);
}

// ---------------- GEMM (m97 structure): C[M][N] = A[M][K] * BT[N][K]^T + bias ----------------

template <int OUT_F32>
__global__ __launch_bounds__(256, 2) void gemm_bt_kernel(
    const unsigned short* __restrict__ A,
    const unsigned short* __restrict__ BT,
    const float* __restrict__ bias,
    void* __restrict__ C, int M, int N, int K,
    int scale_cols, float scale_val) {
  __shared__ unsigned short As[128 * 32];
  __shared__ unsigned short Bs[128 * 32];

  const int tid = threadIdx.x;
  const int wave = tid >> 6;
  const int lane = tid & 63;
  const int quad = lane >> 4;
  const int l16 = lane & 15;
  const int m0 = blockIdx.y * 128;
  const int n0 = blockIdx.x * 128;
  const int wm = (wave >> 1) * 64;
  const int wn = (wave & 1) * 64;

  const size_t a_g = (size_t)(m0 + wave * 32 + (lane >> 2)) * K + (lane & 3) * 8;
  const size_t b_g = (size_t)(n0 + wave * 32 + (lane >> 2)) * K + (lane & 3) * 8;
  unsigned short* lA = As + wave * 1024;
  unsigned short* lB = Bs + wave * 1024;

  f32x4 acc[4][4] = {};

  for (int k0 = 0; k0 < K; k0 += 32) {
    gload_lds16(A + a_g + k0, lA);
    gload_lds16(A + a_g + (size_t)16 * K + k0, lA + 512);
    gload_lds16(BT + b_g + k0, lB);
    gload_lds16(BT + b_g + (size_t)16 * K + k0, lB + 512);
    __syncthreads();

    bf16x8 af[4], bfr[4];
#pragma unroll
    for (int i = 0; i < 4; ++i)
      af[i] = *(const bf16x8*)&As[(wm + i * 16 + l16) * 32 + quad * 8];
#pragma unroll
    for (int i = 0; i < 4; ++i)
      bfr[i] = *(const bf16x8*)&Bs[(wn + i * 16 + l16) * 32 + quad * 8];
#pragma unroll
    for (int mi = 0; mi < 4; ++mi)
#pragma unroll
      for (int ni = 0; ni < 4; ++ni)
        acc[mi][ni] = __builtin_amdgcn_mfma_f32_16x16x32_bf16(af[mi], bfr[ni],
                                                              acc[mi][ni], 0, 0, 0);
    __syncthreads();
  }

#pragma unroll
  for (int mi = 0; mi < 4; ++mi) {
#pragma unroll
    for (int ni = 0; ni < 4; ++ni) {
      const int col = n0 + wn + ni * 16 + l16;
      const int row = m0 + wm + mi * 16 + quad * 4;
      const float bv = bias[col];
      const float sv = (col < scale_cols) ? scale_val : 1.0f;
#pragma unroll
      for (int r = 0; r < 4; ++r) {
        float v = (acc[mi][ni][r] + bv) * sv;
        if (OUT_F32)
          ((float*)C)[(size_t)(row + r) * N + col] = v;
        else
          ((unsigned short*)C)[(size_t)(row + r) * N + col] = f2b(v);
      }
    }
  }
}

// ---------------- flash attention v9: v8 structure, v4-proven scalar ops ----
// v4 shell (QT=64, grid (16,64), 4 blocks/CU, dist-1 prefetch, __syncthreads).
// S^T = K*Q^T via operand swap (layouts jointly pinned by v4's pass; the
// common k-permutation cancels). Lane holds P[q=l16][tok=kc*16+quad*4+r]:
// 4 consecutive toks -> one ds_write_b64 per chunk. PV path bit-identical
// to v4. Row-sum via butterfly (no ones-MFMA).
// CHANGE vs v8 (the discriminating experiment): exp2 via libm exp2f and
// rounding via f2b — the EXACT scalar ops v4 passed with.
// __builtin_amdgcn_exp2f is the prime suspect for v7/v8's identical
// absmax-2.64 failures (only unverified intrinsic in their shared set).

__global__ __launch_bounds__(256, 4) void flash_kernel(
    const unsigned short* __restrict__ qkv,  // [B*S][3072] bf16 (q pre-scaled)
    unsigned short* __restrict__ yatt) {     // [B*S][1024] bf16
  __shared__ unsigned short Ks[2][2][64 * 32];             // 16 KB
  __shared__ __align__(16) unsigned short Vt[8 * 64 * 8];  //  8 KB
  __shared__ __align__(16) unsigned short Ps[4][16 * 72];  //  9 KB (per-wave)

  const int tid = threadIdx.x;
  const int w = tid >> 6;
  const int lane = tid & 63;
  const int quad = lane >> 4;
  const int l16 = lane & 15;
  const int b = blockIdx.y >> 4;
  const int h = blockIdx.y & 15;
  const int jt = blockIdx.x;  // 0..15

  const unsigned short* base = qkv + (size_t)b * SEQ * QKV_LD;

  // K staging: wave w covers toks w*16..+15, both 32-dim halves
  const int ktok_l = w * 16 + (lane >> 2);
  const int ksw = (ktok_l ^ (ktok_l >> 2)) & 3;
  const int kchunk = (lane & 3) ^ ksw;
  const int rsw = (l16 ^ (l16 >> 2)) & 3;  // read-side swizzle (l16-only)

  // V staging: thread covers toks {2vk,2vk+1}, dims vc..vc+7
  const int vk = tid >> 3;
  const int vc = (tid & 7) * 8;
  int vwidx[8];
#pragma unroll
  for (int j = 0; j < 8; ++j)
    vwidx[j] = (vk >> 2) * 256 + (vc | ((j + (vc >> 3)) & 7)) * 4 + (vk & 3);
  // Vt read offsets (shorts): dim = ni*16+l16, rotated slot (v4-verified)
  int vroff[4];
#pragma unroll
  for (int ni = 0; ni < 4; ++ni) {
    const int dim = ni * 16 + l16;
    vroff[ni] = ((dim & 56) | ((dim + (dim >> 3)) & 7)) * 8;
  }

  for (int pass = 0; pass < 2; ++pass) {
    const int qt = pass == 0 ? (31 - jt) : jt;  // long tile first
    const int q0 = qt * 64;
    const int kt = qt + 1;

    // Q fragments (used as B-operand: n=q_row=l16, k=quad*8+j)
    const unsigned short* qp =
        base + (size_t)(q0 + w * 16 + l16) * QKV_LD + h * HD + quad * 8;
    const bf16x8 qf0 = *(const bf16x8*)qp;
    const bf16x8 qf1 = *(const bf16x8*)(qp + 32);

    f32x4 o[4] = {};
    float ls = 0.0f;  // row-sum for q_row = l16 (all quads hold a copy)

    u16x8 va, vb;
    // stage tile 0
    {
      const unsigned short* kg =
          base + (size_t)ktok_l * QKV_LD + DIM + h * HD + kchunk * 8;
      gload_lds16(kg, &Ks[0][0][w * 512]);
      gload_lds16(kg + 32, &Ks[0][1][w * 512]);
      const unsigned short* vg =
          base + (size_t)(2 * vk) * QKV_LD + 2 * DIM + h * HD + vc;
      va = *(const u16x8*)vg;
      vb = *(const u16x8*)(vg + QKV_LD);
    }
    __syncthreads();  // K tile0 in LDS, V tile0 in regs
    {
      u32a* V32 = (u32a*)Vt;
#pragma unroll
      for (int j = 0; j < 8; ++j)
        V32[vwidx[j]] = (unsigned int)va[j] | ((unsigned int)vb[j] << 16);
    }
    __syncthreads();  // V tile0 in LDS

    for (int t = 0; t < kt; ++t) {
      const int cur = t & 1;
      if (t + 1 < kt) {  // async prefetch of tile t+1 (drained at barrier 1)
        const unsigned short* kg =
            base + (size_t)((t + 1) * 64 + ktok_l) * QKV_LD + DIM + h * HD + kchunk * 8;
        gload_lds16(kg, &Ks[1 - cur][0][w * 512]);
        gload_lds16(kg + 32, &Ks[1 - cur][1][w * 512]);
        const unsigned short* vg =
            base + (size_t)((t + 1) * 64 + 2 * vk) * QKV_LD + 2 * DIM + h * HD + vc;
        va = *(const u16x8*)vg;
        vb = *(const u16x8*)(vg + QKV_LD);
      }

      // S^T = K Q^T : A = K-frag (m=k_tok), B = Q-frag (n=q_row).
      // C-layout: row = k_tok = quad*4+r (within 16-chunk kc), col = q = l16.
      const bool diag = (t == kt - 1);
      const int qloc = w * 16 + l16;  // this lane's q-row (column of S^T)
      f32x4 rs = {};
#pragma unroll
      for (int kc = 0; kc < 4; ++kc) {
        const int ro = (kc * 16 + l16) * 32 + ((quad ^ rsw) * 8);
        f32x4 a = {};
        a = __builtin_amdgcn_mfma_f32_16x16x32_bf16(ld_frag16(&Ks[cur][0][ro]),
                                                    qf0, a, 0, 0, 0);
        a = __builtin_amdgcn_mfma_f32_16x16x32_bf16(ld_frag16(&Ks[cur][1][ro]),
                                                    qf1, a, 0, 0, 0);
#pragma unroll
        for (int r = 0; r < 4; ++r) {
          float p = exp2f(a[r]);  // v4-proven libm path
          if (diag && (kc * 16 + quad * 4 + r) > qloc) p = 0.0f;  // causal
          a[r] = p;
        }
        rs += a;
        // pack 4 consecutive toks -> one b64 store into P[q=l16][tok..tok+3]
        u16x4 pk;
        pk.x = f2b(a[0]); pk.y = f2b(a[1]); pk.z = f2b(a[2]); pk.w = f2b(a[3]);
        __builtin_memcpy(&Ps[w][l16 * 72 + kc * 16 + quad * 4], &pk, 8);
      }
      // row-sum for q=l16: horizontal + cross-quad butterfly
      float rsum = (rs.x + rs.y) + (rs.z + rs.w);
      rsum += __shfl_xor(rsum, 16);
      rsum += __shfl_xor(rsum, 32);
      ls += rsum;

      // O += P V  (verified 16x16x32 path, bit-identical reads to v4)
#pragma unroll
      for (int c = 0; c < 2; ++c) {
        const bf16x8 pa = ld_frag16(&Ps[w][l16 * 72 + c * 32 + quad * 8]);
#pragma unroll
        for (int ni = 0; ni < 4; ++ni) {
          const bf16x8 vbf = ld_frag16(&Vt[(c * 4 + quad) * 512 + vroff[ni]]);
          o[ni] = __builtin_amdgcn_mfma_f32_16x16x32_bf16(pa, vbf, o[ni], 0, 0, 0);
        }
      }

      __syncthreads();  // barrier 1: tile-t reads done; drains t+1 prefetch
      if (t + 1 < kt) {
        u32a* V32 = (u32a*)Vt;
#pragma unroll
        for (int j = 0; j < 8; ++j)
          V32[vwidx[j]] = (unsigned int)va[j] | ((unsigned int)vb[j] << 16);
      }
      __syncthreads();  // barrier 2: V tile t+1 visible
    }

    // epilogue: O C-layout rows = quad*4+r (q), cols = ni*16+l16 (dim);
    // denominator for row quad*4+r lives at lane index (quad*4+r).
#pragma unroll
    for (int r = 0; r < 4; ++r) {
      const float lv = __shfl(ls, quad * 4 + r);
      const float inv = 1.0f / lv;
      const int row = q0 + w * 16 + quad * 4 + r;
      unsigned short* dst = yatt + (size_t)(b * SEQ + row) * DIM + h * HD + l16;
#pragma unroll
      for (int ni = 0; ni < 4; ++ni)
        dst[ni * 16] = f2b(o[ni][r] * inv);
    }
  }
}

// ---------------- launch ----------------

extern "C" void kernel_launch(void* const* d_in, const int* in_sizes, int n_in,
                              void* d_out, int out_size, void* d_ws, size_t ws_size,
                              hipStream_t stream) {
  const float* x  = (const float*)d_in[0];   // [4,2048,1024]
  const float* Wa = (const float*)d_in[1];   // [1024,3072]
  const float* ba = (const float*)d_in[2];   // [3072]
  const float* Wp = (const float*)d_in[3];   // [1024,1024]
  const float* bp = (const float*)d_in[4];   // [1024]
  float* out = (float*)d_out;                // [4,2048,1024] fp32

  char* ws = (char*)d_ws;
  unsigned short* xb   = (unsigned short*)ws;                   // 16,777,216 B
  unsigned short* WaT  = (unsigned short*)(ws + 16777216);      //  6,291,456 B
  unsigned short* WpT  = (unsigned short*)(ws + 23068672);      //  2,097,152 B
  unsigned short* qkv  = (unsigned short*)(ws + 25165824);      // 50,331,648 B
  unsigned short* yatt = (unsigned short*)(ws + 75497472);      // 16,777,216 B

  const int M = 4 * SEQ;  // 8192
  const float qscale = 0.125f * 1.44269504089f;  // 1/sqrt(64) * log2(e)

  to_bf16_kernel<<<8192, 256, 0, stream>>>(x, xb, M * DIM);
  transpose_to_bf16_kernel<<<dim3(96, 32), dim3(32, 32), 0, stream>>>(Wa, WaT, DIM, 3 * DIM);
  transpose_to_bf16_kernel<<<dim3(32, 32), dim3(32, 32), 0, stream>>>(Wp, WpT, DIM, DIM);

  gemm_bt_kernel<0><<<dim3(24, 64), 256, 0, stream>>>(xb, WaT, ba, qkv, M, 3 * DIM, DIM,
                                                      DIM, qscale);

  flash_kernel<<<dim3(16, 4 * NH), 256, 0, stream>>>(qkv, yatt);

  gemm_bt_kernel<1><<<dim3(8, 64), 256, 0, stream>>>(yatt, WpT, bp, out, M, DIM, DIM,
                                                     0, 1.0f);
}